// Round 5
// baseline (407.946 us; speedup 1.0000x reference)
//
#include <hip/hip_runtime.h>

typedef int   i32x8 __attribute__((ext_vector_type(8)));
typedef float f32x4 __attribute__((ext_vector_type(4)));

#define B_   8
#define N_   4096
#define D_   256

// fp8 fragment-major blob layout:
//   blob[g16][kt][h] = 1 KB chunk; lane l's 16 bytes at +l*16 hold
//   P[g16*16 + (l&15)][k = kt*128 + (l>>4)*32 + h*16 .. +16]  (e4m3)

__device__ __forceinline__ void gl_lds16(const void* g, void* l) {
  __builtin_amdgcn_global_load_lds(
      (const __attribute__((address_space(1))) unsigned int*)g,
      (__attribute__((address_space(3))) unsigned int*)l, 16, 0, 0);
}

// sum of squares of the 4 e4m3 bytes in w (selector must be a literal)
__device__ __forceinline__ float sq8(unsigned w) {
  float f0 = __builtin_amdgcn_cvt_f32_fp8(w, 0);
  float f1 = __builtin_amdgcn_cvt_f32_fp8(w, 1);
  float f2 = __builtin_amdgcn_cvt_f32_fp8(w, 2);
  float f3 = __builtin_amdgcn_cvt_f32_fp8(w, 3);
  return f0 * f0 + f1 * f1 + f2 * f2 + f3 * f3;
}

// One wave per 16-row group: fp32 -> fp8 e4m3 convert (coalesced 1 KB float4
// reads), in-wave LDS transpose to fragment-major, norms of DEQUANTIZED
// values accumulated during readback, min-init.
__global__ __launch_bounds__(256) void prep_kernel(
    const float* __restrict__ x, const float* __restrict__ y,
    unsigned char* __restrict__ Xf, unsigned char* __restrict__ Yf,
    float* __restrict__ xx, float* __restrict__ yy,
    unsigned* __restrict__ rowmin, unsigned* __restrict__ colmin,
    float* __restrict__ out)
{
  __shared__ unsigned char T[4][16 * 272];   // 16 rows x 256B fp8 (+16 pad)
  if (blockIdx.x == 0 && threadIdx.x == 0) out[0] = 0.f;

  const int wv = threadIdx.x >> 6, lane = threadIdx.x & 63;
  const int wid = (blockIdx.x << 2) + wv;          // 0..4095

  const float* src; unsigned char* dst; float* nrm; unsigned* mn; int g;
  if (wid < 2048) { g = wid;        src = x; dst = Xf; nrm = xx; mn = rowmin; }
  else            { g = wid - 2048; src = y; dst = Yf; nrm = yy; mn = colmin; }

  unsigned char* tw = T[wv];
  const float* rp = src + (size_t)g * 16 * D_;
#pragma unroll
  for (int r = 0; r < 16; ++r) {
    float4 v = *(const float4*)(rp + r * D_ + lane * 4);   // 1 KB contiguous
    unsigned u = __builtin_amdgcn_cvt_pk_fp8_f32(v.x, v.y, 0, 0);
    u = __builtin_amdgcn_cvt_pk_fp8_f32(v.z, v.w, u, 1);   // bytes = x,y,z,w
    *(unsigned*)(tw + r * 272 + lane * 4) = u;
  }
  // Each wave only reads its own T[wv] slice; all cross-lane traffic is
  // intra-wave, so a wave-local lgkmcnt drain replaces the 4-wave rendezvous.
  asm volatile("s_waitcnt lgkmcnt(0)" ::: "memory");
  __builtin_amdgcn_wave_barrier();

  // fragment-order readback: row = lane&15, k-base = (lane>>4)*32
  float s = 0.f;
  const int row = lane & 15, ko = (lane >> 4) * 32;
#pragma unroll
  for (int kt = 0; kt < 2; ++kt)
#pragma unroll
    for (int h = 0; h < 2; ++h) {
      uint4 c = *(const uint4*)(tw + row * 272 + kt * 128 + ko + h * 16);
      s += sq8(c.x) + sq8(c.y) + sq8(c.z) + sq8(c.w);
      *(uint4*)(dst + ((((size_t)g * 2 + kt) * 2 + h) << 10) + lane * 16) = c;
    }
  s += __shfl_xor(s, 16, 64);   // fold quads: row (lane&15)'s full norm
  s += __shfl_xor(s, 32, 64);
  if      (lane < 16) nrm[g * 16 + lane] = s;
  else if (lane < 32) mn[g * 16 + lane - 16] = 0x7f800000u;   // +inf
}

#define SB() __builtin_amdgcn_sched_barrier(0)
#define PBAR() do { SB(); __builtin_amdgcn_s_barrier(); SB(); } while (0)

// MX-fp8 chamfer GEMM (mfma_scale_f32_16x16x128_f8f6f4, scales = 1.0).
// Round-15: schedule restructure (T3+T4+T5). r11/r13/r14 all landed at
// 41-44 us with MfmaUtil 28-31% across different tiles/occupancy -- the
// 2-phase barrier-synced loop's known ~28%-of-peak ceiling (m233). Port of
// the m201 phase template at r14's geometry: 4 phases/group x 2 barriers,
// each phase = {epilogue-slice || 4 ds_read || stage} -> s_barrier ->
// setprio(1) 8 MFMA setprio(0) -> s_barrier. 3-group rotation (6 x 8 KB),
// counted vmcnt(4) ONCE per group, never 0 in-loop (4 gl_lds always in
// flight across barriers). yy moved to LDS so the loop's only VMEM ops are
// the counted gl_lds. sched_barrier(0) pins phase contents.
__global__ __launch_bounds__(256, 2) void chamfer_gemm(
    const unsigned char* __restrict__ Xf, const unsigned char* __restrict__ Yf,
    const float* __restrict__ xx, const float* __restrict__ yy,
    unsigned* __restrict__ rowmin, unsigned* __restrict__ colmin)
{
  __shared__ __align__(16) unsigned char S[6][8192];   // 3-group rotation
  __shared__ unsigned cmin_s[512];                     // col-min table
  __shared__ float    yys[512];                        // yy slice (no loop VMEM)

  const int bid = blockIdx.x;
  const int b   = bid & 7;                   // batch == XCD (L2 locality)
  const int rt  = (bid >> 3) & 15;           // 16 row-tiles of 256
  const int cq  = bid >> 7;                  // 0..7 col-eighths of 512
  const int n0  = rt * 256;
  const int m0  = cq * 512;

  const int t = threadIdx.x, lane = t & 63, wave = t >> 6;
  const int quad = lane >> 4, lcol = lane & 15;

  cmin_s[t]       = 0x7f800000u;
  cmin_s[t + 256] = 0x7f800000u;
  const float* yyp = yy + b * N_ + m0;
  if (t < 128)   // 512 floats = 2 KB; waves 0-1, per-wave linear dst
    gl_lds16((const unsigned char*)yyp + t * 16, (unsigned char*)yys + t * 16);
  __syncthreads();   // publish cmin init + yys (drains the gl_lds)

  // ---- A fragments -> registers (coalesced dwordx4 from fragment blob) ----
  // wave owns 64 rows: g16 = b*256 + rt*16 + wave*4 + i, i = 0..3
  i32x8 af[4][2];
#pragma unroll
  for (int i = 0; i < 4; ++i) {
    const size_t g = (size_t)(b * 256 + rt * 16 + wave * 4 + i);
#pragma unroll
    for (int kt = 0; kt < 2; ++kt) {
      const uint4* p = (const uint4*)(Xf + ((g * 2 + kt) << 11));
      uint4* h = (uint4*)&af[i][kt];
      h[0] = p[lane];        // h=0
      h[1] = p[64 + lane];   // h=1
    }
  }

  float xv[4][4], rmin[4][4];
  const float* xxp = xx + b * N_ + n0 + wave * 64;
#pragma unroll
  for (int i = 0; i < 4; ++i)
#pragma unroll
    for (int r = 0; r < 4; ++r) {
      xv[i][r] = xxp[i * 16 + quad * 4 + r];
      rmin[i][r] = 1e30f;
    }

  // B staging: LDS chunk cd = kt*4 + h*2 + j at cd*1024; slot s = t + h2*256.
  const unsigned char* Ybase = Yf + ((size_t)(b * 256 + cq * 32) << 12);

#define STAGE_B(ct_, buf_)                                                    \
  {                                                                           \
    const unsigned char* Ysrc = Ybase + ((size_t)(ct_) << 13);  /* 2 g16 */   \
    _Pragma("unroll")                                                         \
    for (int h2 = 0; h2 < 2; ++h2) {                                          \
      int s  = t + h2 * 256;                                                  \
      int cd = s >> 6, ln = s & 63;                                           \
      int kt = cd >> 2, hh = (cd >> 1) & 1, jj = cd & 1;                      \
      gl_lds16(Ysrc + jj * 4096 + kt * 2048 + hh * 1024 + ln * 16,            \
               (buf_) + s * 16);                                              \
    }                                                                         \
  }

  // B fragments: bq[j] from chunks (kt, h, j), ds_read_b128 into operand halves
  auto RD = [&](i32x8 (&bq)[2], const unsigned char* buf, int kt) {
#pragma unroll
    for (int j = 0; j < 2; ++j) {
      uint4* h = (uint4*)&bq[j];
      h[0] = *(const uint4*)(buf + (kt * 4 + 0 + j) * 1024 + lane * 16);
      h[1] = *(const uint4*)(buf + (kt * 4 + 2 + j) * 1024 + lane * 16);
    }
  };

  auto MM = [&](f32x4 (&acc)[4][2], i32x8 (&bq)[2], int kt) {
    __builtin_amdgcn_s_setprio(1);
#pragma unroll
    for (int i = 0; i < 4; ++i)
#pragma unroll
      for (int j = 0; j < 2; ++j)
        acc[i][j] = __builtin_amdgcn_mfma_scale_f32_16x16x128_f8f6f4(
            af[i][kt], bq[j], acc[i][j],
            0, 0,        // cbsz = A fmt e4m3, blgp = B fmt e4m3
            0, 127,      // scale A: opsel 0, e8m0 127 = 1.0
            0, 127);     // scale B
    __builtin_amdgcn_s_setprio(0);
  };

  auto ZRO = [&](f32x4 (&acc)[4][2]) {
#pragma unroll
    for (int i = 0; i < 4; ++i)
#pragma unroll
      for (int j = 0; j < 2; ++j) acc[i][j] = f32x4{0.f, 0.f, 0.f, 0.f};
  };

  // epilogue slice for one (ct, j): C/D row = i*16 + quad*4 + r, col = lcol
  auto EPI = [&](f32x4 (&acc)[4][2], int ct, int j) {
    float yv = yys[ct * 32 + j * 16 + lcol];
    float tc[16];
#pragma unroll
    for (int i = 0; i < 4; ++i)
#pragma unroll
      for (int r = 0; r < 4; ++r) {
        float a = acc[i][j][r];
        rmin[i][r] = fminf(rmin[i][r], __builtin_fmaf(-2.0f, a, yv));
        tc[i * 4 + r] = __builtin_fmaf(-2.0f, a, xv[i][r]);
      }
    float m0_ = fminf(fminf(tc[0], tc[1]), fminf(tc[2], tc[3]));
    float m1_ = fminf(fminf(tc[4], tc[5]), fminf(tc[6], tc[7]));
    float m2_ = fminf(fminf(tc[8], tc[9]), fminf(tc[10], tc[11]));
    float m3_ = fminf(fminf(tc[12], tc[13]), fminf(tc[14], tc[15]));
    float cm  = fminf(fminf(m0_, m1_), fminf(m2_, m3_));
    // 64-lane fire-and-forget; quads merge inside the one ds_min issue
    atomicMin(&cmin_s[ct * 32 + j * 16 + lcol], __float_as_uint(cm + yv));
  };

  // prologue: stage group 0 (cts 0,1 -> S0,S1) and group 1 (cts 2,3 -> S2,S3)
  STAGE_B(0, S[0]);
  STAGE_B(1, S[1]);
  STAGE_B(2, S[2]);
  STAGE_B(3, S[3]);
  __syncthreads();   // one-time full drain: pairs 0 AND 1 published

  i32x8 bq0[2], bq1[2];
  f32x4 accA[4][2], accB[4][2];

#pragma unroll
  for (int g = 0; g < 8; ++g) {
    const int ctA = 2 * g, ctB = 2 * g + 1;
    const unsigned char* bufA = S[2 * (g % 3)];
    const unsigned char* bufB = S[2 * (g % 3) + 1];
    unsigned char* stA = S[2 * ((g + 2) % 3)];       // == pair of group g-1:
    unsigned char* stB = S[2 * ((g + 2) % 3) + 1];   // free after its barrier

    // ph1: epi(prevB,j0) || zero accA || read bqA.kt0 || stage next.A
    if (g > 0) EPI(accB, ctA - 1, 0);
    ZRO(accA);
    RD(bq0, bufA, 0);
    if (g <= 5) STAGE_B(2 * (g + 2), stA);
    PBAR();
    MM(accA, bq0, 0);
    PBAR();

    // ph2: epi(prevB,j1) || read bqA.kt1 || stage next.B
    if (g > 0) EPI(accB, ctA - 1, 1);
    RD(bq1, bufA, 1);
    if (g <= 5) STAGE_B(2 * (g + 2) + 1, stB);
    PBAR();
    MM(accA, bq1, 1);
    PBAR();

    // ph3: epi(A,j0) || zero accB || read bqB.kt0
    EPI(accA, ctA, 0);
    ZRO(accB);
    RD(bq0, bufB, 0);
    PBAR();
    MM(accB, bq0, 0);
    PBAR();

    // ph4: epi(A,j1) || read bqB.kt1; counted vmcnt publishes pair(g+1)
    EPI(accA, ctA, 1);
    RD(bq1, bufB, 1);
    PBAR();
    MM(accB, bq1, 1);
    SB();
    if (g <= 5)      asm volatile("s_waitcnt vmcnt(4)" ::: "memory");
    else if (g == 6) asm volatile("s_waitcnt vmcnt(0)" ::: "memory");
    PBAR();
  }
  EPI(accB, 15, 0);   // tail: last ct's epilogue
  EPI(accB, 15, 1);

  // rowmin: one global atomic set per block (64 rows/wave)
#pragma unroll
  for (int i = 0; i < 4; ++i)
#pragma unroll
    for (int r = 0; r < 4; ++r) {
      float v = xv[i][r] + rmin[i][r];
#pragma unroll
      for (int m = 1; m < 16; m <<= 1) v = fminf(v, __shfl_xor(v, m, 64));
      if (lcol == 0)
        atomicMin(rowmin + b * N_ + n0 + wave * 64 + i * 16 + quad * 4 + r,
                  __float_as_uint(v));
    }

  __syncthreads();
  // colmin: flush LDS table to global
#pragma unroll
  for (int i = 0; i < 2; ++i) {
    int idx = t + i * 256;
    atomicMin(colmin + b * N_ + m0 + idx, cmin_s[idx]);
  }
#undef STAGE_B
}

// 64 blocks x 256 threads: 16384 uint4 = 65536 mins; wave-reduce + atomicAdd.
__global__ __launch_bounds__(256) void reduce_kernel(
    const unsigned* __restrict__ mins,   // rowmin then colmin, contiguous
    float* __restrict__ out)
{
  int idx = blockIdx.x * 256 + threadIdx.x;
  uint4 u = ((const uint4*)mins)[idx];
  float s = __uint_as_float(u.x) + __uint_as_float(u.y)
          + __uint_as_float(u.z) + __uint_as_float(u.w);
#pragma unroll
  for (int m = 1; m < 64; m <<= 1) s += __shfl_xor(s, m, 64);
  if ((threadIdx.x & 63) == 0) atomicAdd(out, s);
}

extern "C" void kernel_launch(void* const* d_in, const int* in_sizes, int n_in,
                              void* d_out, int out_size, void* d_ws, size_t ws_size,
                              hipStream_t stream) {
  const float* gts   = (const float*)d_in[0];   // [8,4096,256] fp32
  const float* preds = (const float*)d_in[1];   // [8,4096,256] fp32

  char* ws = (char*)d_ws;
  const size_t XB_BYTES = (size_t)B_ * N_ * D_;         // 8 MiB each (fp8)
  unsigned char* Xf     = (unsigned char*)ws;
  unsigned char* Yf     = (unsigned char*)(ws + XB_BYTES);
  float*    xx     = (float*)(ws + 2 * XB_BYTES);
  float*    yy     = (float*)(ws + 2 * XB_BYTES + (size_t)B_ * N_ * 4);
  unsigned* rowmin = (unsigned*)(ws + 2 * XB_BYTES + (size_t)B_ * N_ * 8);
  unsigned* colmin = (unsigned*)(ws + 2 * XB_BYTES + (size_t)B_ * N_ * 12);

  // 4096 row-groups of 16 (X then Y), one wave each -> 1024 blocks
  prep_kernel<<<1024, 256, 0, stream>>>(gts, preds, Xf, Yf, xx, yy, rowmin, colmin,
                                        (float*)d_out);

  // 8 batches x 16 row-tiles(256) x 8 col-eighths(512) = 1024 blocks
  chamfer_gemm<<<1024, 256, 0, stream>>>(Xf, Yf, xx, yy, rowmin, colmin);

  reduce_kernel<<<64, 256, 0, stream>>>(rowmin, (float*)d_out);
}

// Round 6
// 137.729 us; speedup vs baseline: 2.9619x; 2.9619x over previous
//
#include <hip/hip_runtime.h>

typedef int   i32x8 __attribute__((ext_vector_type(8)));
typedef float f32x4 __attribute__((ext_vector_type(4)));

#define B_   8
#define N_   4096
#define D_   256

// fp8 fragment-major blob layout:
//   blob[g16][kt][h] = 1 KB chunk; lane l's 16 bytes at +l*16 hold
//   P[g16*16 + (l&15)][k = kt*128 + (l>>4)*32 + h*16 .. +16]  (e4m3)

__device__ __forceinline__ void gl_lds16(const void* g, void* l) {
  __builtin_amdgcn_global_load_lds(
      (const __attribute__((address_space(1))) unsigned int*)g,
      (__attribute__((address_space(3))) unsigned int*)l, 16, 0, 0);
}

// sum of squares of the 4 e4m3 bytes in w (selector must be a literal)
__device__ __forceinline__ float sq8(unsigned w) {
  float f0 = __builtin_amdgcn_cvt_f32_fp8(w, 0);
  float f1 = __builtin_amdgcn_cvt_f32_fp8(w, 1);
  float f2 = __builtin_amdgcn_cvt_f32_fp8(w, 2);
  float f3 = __builtin_amdgcn_cvt_f32_fp8(w, 3);
  return f0 * f0 + f1 * f1 + f2 * f2 + f3 * f3;
}

// One wave per 16-row group: fp32 -> fp8 e4m3 convert (coalesced 1 KB float4
// reads), in-wave LDS transpose to fragment-major, norms of DEQUANTIZED
// values accumulated during readback, min-init.
__global__ __launch_bounds__(256) void prep_kernel(
    const float* __restrict__ x, const float* __restrict__ y,
    unsigned char* __restrict__ Xf, unsigned char* __restrict__ Yf,
    float* __restrict__ xx, float* __restrict__ yy,
    unsigned* __restrict__ rowmin, unsigned* __restrict__ colmin,
    float* __restrict__ out)
{
  __shared__ unsigned char T[4][16 * 272];   // 16 rows x 256B fp8 (+16 pad)
  if (blockIdx.x == 0 && threadIdx.x == 0) out[0] = 0.f;

  const int wv = threadIdx.x >> 6, lane = threadIdx.x & 63;
  const int wid = (blockIdx.x << 2) + wv;          // 0..4095

  const float* src; unsigned char* dst; float* nrm; unsigned* mn; int g;
  if (wid < 2048) { g = wid;        src = x; dst = Xf; nrm = xx; mn = rowmin; }
  else            { g = wid - 2048; src = y; dst = Yf; nrm = yy; mn = colmin; }

  unsigned char* tw = T[wv];
  const float* rp = src + (size_t)g * 16 * D_;
#pragma unroll
  for (int r = 0; r < 16; ++r) {
    float4 v = *(const float4*)(rp + r * D_ + lane * 4);   // 1 KB contiguous
    unsigned u = __builtin_amdgcn_cvt_pk_fp8_f32(v.x, v.y, 0, 0);
    u = __builtin_amdgcn_cvt_pk_fp8_f32(v.z, v.w, u, 1);   // bytes = x,y,z,w
    *(unsigned*)(tw + r * 272 + lane * 4) = u;
  }
  // Each wave only reads its own T[wv] slice; all cross-lane traffic is
  // intra-wave, so a wave-local lgkmcnt drain replaces the 4-wave rendezvous.
  asm volatile("s_waitcnt lgkmcnt(0)" ::: "memory");
  __builtin_amdgcn_wave_barrier();

  // fragment-order readback: row = lane&15, k-base = (lane>>4)*32
  float s = 0.f;
  const int row = lane & 15, ko = (lane >> 4) * 32;
#pragma unroll
  for (int kt = 0; kt < 2; ++kt)
#pragma unroll
    for (int h = 0; h < 2; ++h) {
      uint4 c = *(const uint4*)(tw + row * 272 + kt * 128 + ko + h * 16);
      s += sq8(c.x) + sq8(c.y) + sq8(c.z) + sq8(c.w);
      *(uint4*)(dst + ((((size_t)g * 2 + kt) * 2 + h) << 10) + lane * 16) = c;
    }
  s += __shfl_xor(s, 16, 64);   // fold quads: row (lane&15)'s full norm
  s += __shfl_xor(s, 32, 64);
  if      (lane < 16) nrm[g * 16 + lane] = s;
  else if (lane < 32) mn[g * 16 + lane - 16] = 0x7f800000u;   // +inf
}

// MX-fp8 chamfer GEMM (mfma_scale_f32_16x16x128_f8f6f4, scales = 1.0).
// Round-16: T4 (counted vmcnt, never drain-to-0) at r14's geometry, with
// r15's spill lesson applied: SINGLE acc + bq, both local to the ct body
// (dead across barriers), rolled loop, no sched_barrier. Per-ct pipeline:
// 4-deep 8 KB buffer rotation (same 36 KB LDS, 4 blocks/CU), stage 3 ahead,
// each __syncthreads replaced by {s_waitcnt vmcnt(4); s_barrier} -- 4 loads
// (= 2 ct-stages) stay in flight across every barrier; tail peels
// vmcnt(2)/vmcnt(0). One barrier/ct is race-free: MM's lgkm data wait
// closes the read window before any wave can reach the next barrier, and
// the stage target is always 3 ct ahead.
__global__ __launch_bounds__(256, 2) void chamfer_gemm(
    const unsigned char* __restrict__ Xf, const unsigned char* __restrict__ Yf,
    const float* __restrict__ xx, const float* __restrict__ yy,
    unsigned* __restrict__ rowmin, unsigned* __restrict__ colmin)
{
  __shared__ __align__(16) unsigned char S[4][8192];   // 4-deep ct rotation
  __shared__ unsigned cmin_s[512];                     // col-min table
  __shared__ float    yys[512];                        // yy slice (no loop VMEM)

  const int bid = blockIdx.x;
  const int b   = bid & 7;                   // batch == XCD (L2 locality)
  const int rt  = (bid >> 3) & 15;           // 16 row-tiles of 256
  const int cq  = bid >> 7;                  // 0..7 col-eighths of 512
  const int n0  = rt * 256;
  const int m0  = cq * 512;

  const int t = threadIdx.x, lane = t & 63, wave = t >> 6;
  const int quad = lane >> 4, lcol = lane & 15;

  cmin_s[t]       = 0x7f800000u;
  cmin_s[t + 256] = 0x7f800000u;
  const float* yyp = yy + b * N_ + m0;
  if (t < 128)   // 512 floats = 2 KB
    gl_lds16((const unsigned char*)yyp + t * 16, (unsigned char*)yys + t * 16);

  // ---- A fragments -> registers (coalesced dwordx4 from fragment blob) ----
  // wave owns 64 rows: g16 = b*256 + rt*16 + wave*4 + i, i = 0..3
  i32x8 af[4][2];
#pragma unroll
  for (int i = 0; i < 4; ++i) {
    const size_t g = (size_t)(b * 256 + rt * 16 + wave * 4 + i);
#pragma unroll
    for (int kt = 0; kt < 2; ++kt) {
      const uint4* p = (const uint4*)(Xf + ((g * 2 + kt) << 11));
      uint4* h = (uint4*)&af[i][kt];
      h[0] = p[lane];        // h=0
      h[1] = p[64 + lane];   // h=1
    }
  }

  float xv[4][4], rmin[4][4];
  const float* xxp = xx + b * N_ + n0 + wave * 64;
#pragma unroll
  for (int i = 0; i < 4; ++i)
#pragma unroll
    for (int r = 0; r < 4; ++r) {
      xv[i][r] = xxp[i * 16 + quad * 4 + r];
      rmin[i][r] = 1e30f;
    }

  // B staging: ct = 32 cols = 2 contiguous g16 blobs = 8 KB; LDS chunk
  // cd = kt*4 + h*2 + j at cd*1024, slot s = t + h2*256 (as before).
  const unsigned char* Ybase = Yf + ((size_t)(b * 256 + cq * 32) << 12);

#define STAGE_B(ct_, buf_)                                                    \
  {                                                                           \
    const unsigned char* Ysrc = Ybase + ((size_t)(ct_) << 13);  /* 2 g16 */   \
    _Pragma("unroll")                                                         \
    for (int h2 = 0; h2 < 2; ++h2) {                                          \
      int s  = t + h2 * 256;                                                  \
      int cd = s >> 6, ln = s & 63;                                           \
      int kt = cd >> 2, hh = (cd >> 1) & 1, jj = cd & 1;                      \
      gl_lds16(Ysrc + jj * 4096 + kt * 2048 + hh * 1024 + ln * 16,            \
               (buf_) + s * 16);                                              \
    }                                                                         \
  }

  // prologue: stage cts 0,1,2; full one-time drain publishes everything
  STAGE_B(0, S[0]);
  STAGE_B(1, S[1]);
  STAGE_B(2, S[2]);
  __syncthreads();

  // ct body: acc/bq local => dead across barriers (register envelope = r14)
  auto do_ct = [&](int ct, const unsigned char* curb) {
    // B fragments: bq[j][kt] from chunks (kt, h, j), b128 into operand halves
    i32x8 bq[2][2];
#pragma unroll
    for (int j = 0; j < 2; ++j)
#pragma unroll
      for (int kt = 0; kt < 2; ++kt) {
        uint4* h = (uint4*)&bq[j][kt];
        h[0] = *(const uint4*)(curb + (kt * 4 + 0 + j) * 1024 + lane * 16);
        h[1] = *(const uint4*)(curb + (kt * 4 + 2 + j) * 1024 + lane * 16);
      }

    f32x4 acc[4][2] = {};
    __builtin_amdgcn_s_setprio(1);
#pragma unroll
    for (int kt = 0; kt < 2; ++kt)
#pragma unroll
      for (int i = 0; i < 4; ++i)
#pragma unroll
        for (int j = 0; j < 2; ++j)
          acc[i][j] = __builtin_amdgcn_mfma_scale_f32_16x16x128_f8f6f4(
              af[i][kt], bq[j][kt], acc[i][j],
              0, 0,        // cbsz = A fmt e4m3, blgp = B fmt e4m3
              0, 127,      // scale A: opsel 0, e8m0 127 = 1.0
              0, 127);     // scale B
    __builtin_amdgcn_s_setprio(0);

    // epilogue: C/D row = i*16 + quad*4 + r, col = j*16 + lcol
#pragma unroll
    for (int j = 0; j < 2; ++j) {
      float yv = yys[ct * 32 + j * 16 + lcol];
      float tc[16];
#pragma unroll
      for (int i = 0; i < 4; ++i)
#pragma unroll
        for (int r = 0; r < 4; ++r) {
          float a = acc[i][j][r];
          rmin[i][r] = fminf(rmin[i][r], __builtin_fmaf(-2.0f, a, yv));
          tc[i * 4 + r] = __builtin_fmaf(-2.0f, a, xv[i][r]);
        }
      float m0_ = fminf(fminf(tc[0], tc[1]), fminf(tc[2], tc[3]));
      float m1_ = fminf(fminf(tc[4], tc[5]), fminf(tc[6], tc[7]));
      float m2_ = fminf(fminf(tc[8], tc[9]), fminf(tc[10], tc[11]));
      float m3_ = fminf(fminf(tc[12], tc[13]), fminf(tc[14], tc[15]));
      float cm  = fminf(fminf(m0_, m1_), fminf(m2_, m3_));
      // 64-lane fire-and-forget; quads merge inside the one ds_min issue
      atomicMin(&cmin_s[ct * 32 + j * 16 + lcol], __float_as_uint(cm + yv));
    }
  };

  for (int ct = 0; ct < 14; ++ct) {
    // buffer ct ready iff <= 4 newer loads (stages ct+1, ct+2) outstanding
    asm volatile("s_waitcnt vmcnt(4)" ::: "memory");
    __builtin_amdgcn_s_barrier();
    if (ct < 13) STAGE_B(ct + 3, S[(ct + 3) & 3]);   // 3 ahead
    do_ct(ct, S[ct & 3]);
  }
  asm volatile("s_waitcnt vmcnt(2)" ::: "memory");   // only ct15's 2 in flight
  __builtin_amdgcn_s_barrier();
  do_ct(14, S[14 & 3]);
  asm volatile("s_waitcnt vmcnt(0)" ::: "memory");   // final drain
  __builtin_amdgcn_s_barrier();
  do_ct(15, S[15 & 3]);

  // rowmin: one global atomic set per block (64 rows/wave)
#pragma unroll
  for (int i = 0; i < 4; ++i)
#pragma unroll
    for (int r = 0; r < 4; ++r) {
      float v = xv[i][r] + rmin[i][r];
#pragma unroll
      for (int m = 1; m < 16; m <<= 1) v = fminf(v, __shfl_xor(v, m, 64));
      if (lcol == 0)
        atomicMin(rowmin + b * N_ + n0 + wave * 64 + i * 16 + quad * 4 + r,
                  __float_as_uint(v));
    }

  __syncthreads();
  // colmin: flush LDS table to global
#pragma unroll
  for (int i = 0; i < 2; ++i) {
    int idx = t + i * 256;
    atomicMin(colmin + b * N_ + m0 + idx, cmin_s[idx]);
  }
#undef STAGE_B
}

// 64 blocks x 256 threads: 16384 uint4 = 65536 mins; wave-reduce + atomicAdd.
__global__ __launch_bounds__(256) void reduce_kernel(
    const unsigned* __restrict__ mins,   // rowmin then colmin, contiguous
    float* __restrict__ out)
{
  int idx = blockIdx.x * 256 + threadIdx.x;
  uint4 u = ((const uint4*)mins)[idx];
  float s = __uint_as_float(u.x) + __uint_as_float(u.y)
          + __uint_as_float(u.z) + __uint_as_float(u.w);
#pragma unroll
  for (int m = 1; m < 64; m <<= 1) s += __shfl_xor(s, m, 64);
  if ((threadIdx.x & 63) == 0) atomicAdd(out, s);
}

extern "C" void kernel_launch(void* const* d_in, const int* in_sizes, int n_in,
                              void* d_out, int out_size, void* d_ws, size_t ws_size,
                              hipStream_t stream) {
  const float* gts   = (const float*)d_in[0];   // [8,4096,256] fp32
  const float* preds = (const float*)d_in[1];   // [8,4096,256] fp32

  char* ws = (char*)d_ws;
  const size_t XB_BYTES = (size_t)B_ * N_ * D_;         // 8 MiB each (fp8)
  unsigned char* Xf     = (unsigned char*)ws;
  unsigned char* Yf     = (unsigned char*)(ws + XB_BYTES);
  float*    xx     = (float*)(ws + 2 * XB_BYTES);
  float*    yy     = (float*)(ws + 2 * XB_BYTES + (size_t)B_ * N_ * 4);
  unsigned* rowmin = (unsigned*)(ws + 2 * XB_BYTES + (size_t)B_ * N_ * 8);
  unsigned* colmin = (unsigned*)(ws + 2 * XB_BYTES + (size_t)B_ * N_ * 12);

  // 4096 row-groups of 16 (X then Y), one wave each -> 1024 blocks
  prep_kernel<<<1024, 256, 0, stream>>>(gts, preds, Xf, Yf, xx, yy, rowmin, colmin,
                                        (float*)d_out);

  // 8 batches x 16 row-tiles(256) x 8 col-eighths(512) = 1024 blocks
  chamfer_gemm<<<1024, 256, 0, stream>>>(Xf, Yf, xx, yy, rowmin, colmin);

  reduce_kernel<<<64, 256, 0, stream>>>(rowmin, (float*)d_out);
}